// Round 8
// baseline (1674.036 us; speedup 1.0000x reference)
//
#include <hip/hip_runtime.h>
#include <hip/hip_bf16.h>
#include <stdint.h>

#define HIDDEN 4096
#define INTER  14336
#define NSEL   4096

using short8 = __attribute__((ext_vector_type(8))) short;
using f32x4  = __attribute__((ext_vector_type(4))) float;

__device__ __forceinline__ uint16_t f2bf(float f) {
  uint32_t u = __float_as_uint(f);
  uint32_t r = (u + 0x7FFFu + ((u >> 16) & 1u)) >> 16;
  return (uint16_t)r;
}
__device__ __forceinline__ float bf2f(uint16_t h) {
  return __uint_as_float(((uint32_t)h) << 16);
}
__device__ __forceinline__ uint32_t pack2(float lo, float hi) {
  return (uint32_t)f2bf(lo) | ((uint32_t)f2bf(hi) << 16);
}

// ---- gather selected tokens (blocks < NSEL) + Wg fp32->bf16 cvt tail ----
__global__ void gather_cast(const float* __restrict__ x, const int* __restrict__ idx,
                            uint16_t* __restrict__ xs,
                            const float* __restrict__ cvtIn, uint16_t* __restrict__ cvtOut) {
  const int b = blockIdx.x;
  const int t = threadIdx.x;
  if (b >= NSEL) {           // cvt tail: 64 elems/thread
    const int cb = b - NSEL;
#pragma unroll
    for (int k = 0; k < 8; ++k) {
      const size_t i = (size_t)cb * 16384 + (size_t)k * 2048 + (size_t)t * 8;
      float4 a = *(const float4*)(cvtIn + i);
      float4 c = *(const float4*)(cvtIn + i + 4);
      uint4 v;
      v.x = pack2(a.x, a.y); v.y = pack2(a.z, a.w);
      v.z = pack2(c.x, c.y); v.w = pack2(c.z, c.w);
      *(uint4*)(cvtOut + i) = v;
    }
    return;
  }
  const size_t s = (size_t)idx[b] * HIDDEN + (size_t)t * 16;
  const size_t d = (size_t)b * HIDDEN + (size_t)t * 16;
  const float4* sp = (const float4*)(x + s);
  float4 f0 = sp[0], f1 = sp[1], f2 = sp[2], f3 = sp[3];
  uint4 v0, v1;
  v0.x = pack2(f0.x, f0.y); v0.y = pack2(f0.z, f0.w);
  v0.z = pack2(f1.x, f1.y); v0.w = pack2(f1.z, f1.w);
  v1.x = pack2(f2.x, f2.y); v1.y = pack2(f2.z, f2.w);
  v1.z = pack2(f3.x, f3.y); v1.w = pack2(f3.z, f3.w);
  *(uint4*)(xs + d)     = v0;
  *(uint4*)(xs + d + 8) = v1;
}

__device__ __forceinline__ void gload16(const void* g, void* l) {
  __builtin_amdgcn_global_load_lds(
      (const __attribute__((address_space(1))) void*)g,
      (__attribute__((address_space(3))) void*)l, 16, 0, 0);
}

// ============================================================================
// NT GEMM: C[M][N] = A[M][K]*B[N][K]^T, bf16 in, fp32 acc.
// m201-faithful 8-phase schedule adapted to NT inputs:
// 256x256 tile, BK=64, 8 waves (2M x 4N) of 128x64, 512 threads, 16x16x32
// MFMA, 128 KiB double-buffered LDS. 4 phases per K64-tile, each phase:
//   {4-8 ds_read_b128 | stage ONE half-tile (2 gload_lds/thread)}
//   -> s_barrier -> lgkmcnt(0)+sched_barrier -> setprio(1) -> 16 MFMA
//   -> setprio(0) [-> counted vmcnt] -> s_barrier
// Half-tiles: A split by rows (h0=rows 0-127, h1=128-255; wave wm reads only
// half wm), B split by k-slice (s0=k 0-31, s1=k 32-63). Staged during tile t
// into buf^1 at phases 0..3 = A0,A1,B0,B1. Certification chain (counted,
// never 0 mid-loop): end-P1 vmcnt(4) certifies B1(t) for P2; end-P3 vmcnt(2)
// certifies A0,A1,B0(t+1) for next P0.
// LDS swizzle (validated by the r6-measured quarter-wave rule: each 16-lane
// group must hit 8 distinct 16B slots):
//  A: row r = 128B line of 8 slots; stored slot' = kslot ^ (r&7),
//     kslot = ks*4+lg. Reads: slot' = lr&7-driven -> 2-way max (free).
//  B: per-kslice segment, line = 2 rows x 32 cols; slot' = ((r&1)*4+lg)^(line&7)
//     (exactly r6's proven-zero layout). Staged via pre-inverse-swizzled
//     GLOBAL source + LINEAR gload_lds dest (rule 21).
// T1 bijective XCD swizzle, bm-fastest. T5 setprio around MFMA clusters.
// Fused epilogue-cvt: each gemm block converts 65536 elems of the NEXT
// GEMM's weight fp32->bf16 after its C-write (stream-ordered consumer).
// EPI 0: store bf16 g. EPI 1: h = silu(g)*acc overwrite. EPI 2: out=acc*wt.
// ============================================================================
template<int EPI>
__global__ __launch_bounds__(512, 2) void gemm_nt(
    const uint16_t* __restrict__ A,
    const uint16_t* __restrict__ B,
    uint16_t* __restrict__ G,
    float* __restrict__ O,
    const float* __restrict__ Wt,
    int N, int K, int nbm,
    const float* __restrict__ cvtIn, uint16_t* __restrict__ cvtOut)
{
  __shared__ __align__(16) uint16_t lds[2][32768];  // buf: A[0..16383] B[16384..32767]

  const int nwg = (int)gridDim.x;
  const int bid = (int)blockIdx.x;
  const int lid = (bid & 7) * (nwg >> 3) + (bid >> 3);
  const int bm = lid % nbm, bn = lid / nbm;

  const int tid  = (int)threadIdx.x;
  const int lane = tid & 63, w = tid >> 6;
  const int wm = w >> 2, wn = w & 3;       // wave tile: rows wm*128, cols wn*64
  const int lr = lane & 15, lg = lane >> 4;

  // ---- read offsets (u16, buf-relative) ----
  // A: off(ks,m) = wm*8192 + (m*16+lr)*64 + ((ks*4+lg)^(lr&7))*8
  const int aOffK0 = wm * 8192 + lr * 64 + ((lg ^ (lr & 7)) * 8);
  const int aOffK1 = wm * 8192 + lr * 64 + (((4 + lg) ^ (lr & 7)) * 8);
  // B: off(ks,n) = 16384 + ks*8192 + (wn*32 + n*8 + (lr>>1))*64
  //               + ((((lr&1)*4)|lg) ^ (lr>>1))*8
  const int bSl   = ((((lr & 1) << 2) | lg) ^ (lr >> 1)) * 8;
  const int bOffK0 = 16384 + wn * 2048 + (lr >> 1) * 64 + bSl;
  const int bOffK1 = bOffK0 + 8192;

  // ---- staging precompute (inverse-swizzled global source) ----
  // A half h: thread covers LDS j*8, j = tid (load0) / 512+tid (load1).
  // row = j>>3 (+h*128), slot' = j&7, global kslot = slot' ^ (row&7).
  const int rA  = tid >> 3;
  const int slA = (tid & 7) ^ (rA & 7);
  const uint16_t* aS0 = A + (size_t)(bm * 256 + rA) * K + slA * 8;
  const uint16_t* aS1 = aS0 + (size_t)128 * K;
  // B kslice s: line = j>>3, slot' = j&7, s0 = slot'^(line&7),
  // row = line*2 + (s0>>2), col16 = (s0&3)*8.
  const int s0B = (tid & 7) ^ ((tid >> 3) & 7);
  const int rB  = (tid >> 3) * 2 + (s0B >> 2);
  const uint16_t* bS = B + (size_t)(bn * 256 + rB) * K + (s0B & 3) * 8;
  const size_t bStep = (size_t)128 * K;   // load1 = +128 rows

#define STAGE_AH(tt, q, h) do { \
    const uint16_t* _s = ((h) ? aS1 : aS0) + (size_t)(tt) * 64; \
    gload16(_s,                  &lds[q][(h) * 8192 + tid * 8]); \
    gload16(_s + (size_t)64 * K, &lds[q][(h) * 8192 + 4096 + tid * 8]); \
  } while (0)
#define STAGE_BS(tt, q, s) do { \
    const uint16_t* _s = bS + (size_t)(tt) * 64 + (s) * 32; \
    gload16(_s,         &lds[q][16384 + (s) * 8192 + tid * 8]); \
    gload16(_s + bStep, &lds[q][16384 + (s) * 8192 + 4096 + tid * 8]); \
  } while (0)

  f32x4 acc[8][4];
#pragma unroll
  for (int m = 0; m < 8; ++m)
#pragma unroll
    for (int n = 0; n < 4; ++n)
#pragma unroll
      for (int j = 0; j < 4; ++j) acc[m][n][j] = 0.f;

  const int nk = K >> 6;

  // prologue: stage full tile 0 (8 loads); certify A0,A1,B0 (B1 in flight)
  STAGE_AH(0, 0, 0); STAGE_AH(0, 0, 1);
  STAGE_BS(0, 0, 0); STAGE_BS(0, 0, 1);
  asm volatile("s_waitcnt vmcnt(2)" ::: "memory");
  __builtin_amdgcn_s_barrier();

  for (int t = 0; t < nk; ++t) {
    const int p = t & 1, q = p ^ 1;
    const uint16_t* S = &lds[p][0];
    const bool pre = (t + 1 < nk);
    short8 av[4], bv0[4], bv1[4];

    // ---------------- phase 0: m0-3 x ks0 ----------------
#pragma unroll
    for (int m = 0; m < 4; ++m) av[m]  = *(const short8*)&S[aOffK0 + m * 1024];
#pragma unroll
    for (int n = 0; n < 4; ++n) bv0[n] = *(const short8*)&S[bOffK0 + n * 512];
    if (pre) STAGE_AH(t + 1, q, 0);
    __builtin_amdgcn_s_barrier();
    asm volatile("s_waitcnt lgkmcnt(0)" ::: "memory");
    __builtin_amdgcn_sched_barrier(0);
    __builtin_amdgcn_s_setprio(1);
#pragma unroll
    for (int m = 0; m < 4; ++m)
#pragma unroll
      for (int n = 0; n < 4; ++n)
        acc[m][n] = __builtin_amdgcn_mfma_f32_16x16x32_bf16(av[m], bv0[n], acc[m][n], 0, 0, 0);
    __builtin_amdgcn_s_setprio(0);
    __builtin_amdgcn_s_barrier();

    // ---------------- phase 1: m4-7 x ks0 ----------------
#pragma unroll
    for (int m = 0; m < 4; ++m) av[m] = *(const short8*)&S[aOffK0 + (4 + m) * 1024];
    if (pre) STAGE_AH(t + 1, q, 1);
    __builtin_amdgcn_s_barrier();
    asm volatile("s_waitcnt lgkmcnt(0)" ::: "memory");
    __builtin_amdgcn_sched_barrier(0);
    __builtin_amdgcn_s_setprio(1);
#pragma unroll
    for (int m = 0; m < 4; ++m)
#pragma unroll
      for (int n = 0; n < 4; ++n)
        acc[4 + m][n] = __builtin_amdgcn_mfma_f32_16x16x32_bf16(av[m], bv0[n], acc[4 + m][n], 0, 0, 0);
    __builtin_amdgcn_s_setprio(0);
    if (pre) { asm volatile("s_waitcnt vmcnt(4)" ::: "memory"); }  // certify B1(t)
    else     { asm volatile("s_waitcnt vmcnt(0)" ::: "memory"); }
    __builtin_amdgcn_s_barrier();

    // ---------------- phase 2: m0-3 x ks1 ----------------
#pragma unroll
    for (int m = 0; m < 4; ++m) av[m]  = *(const short8*)&S[aOffK1 + m * 1024];
#pragma unroll
    for (int n = 0; n < 4; ++n) bv1[n] = *(const short8*)&S[bOffK1 + n * 512];
    if (pre) STAGE_BS(t + 1, q, 0);
    __builtin_amdgcn_s_barrier();
    asm volatile("s_waitcnt lgkmcnt(0)" ::: "memory");
    __builtin_amdgcn_sched_barrier(0);
    __builtin_amdgcn_s_setprio(1);
#pragma unroll
    for (int m = 0; m < 4; ++m)
#pragma unroll
      for (int n = 0; n < 4; ++n)
        acc[m][n] = __builtin_amdgcn_mfma_f32_16x16x32_bf16(av[m], bv1[n], acc[m][n], 0, 0, 0);
    __builtin_amdgcn_s_setprio(0);
    __builtin_amdgcn_s_barrier();

    // ---------------- phase 3: m4-7 x ks1 ----------------
#pragma unroll
    for (int m = 0; m < 4; ++m) av[m] = *(const short8*)&S[aOffK1 + (4 + m) * 1024];
    if (pre) STAGE_BS(t + 1, q, 1);
    __builtin_amdgcn_s_barrier();
    asm volatile("s_waitcnt lgkmcnt(0)" ::: "memory");
    __builtin_amdgcn_sched_barrier(0);
    __builtin_amdgcn_s_setprio(1);
#pragma unroll
    for (int m = 0; m < 4; ++m)
#pragma unroll
      for (int n = 0; n < 4; ++n)
        acc[4 + m][n] = __builtin_amdgcn_mfma_f32_16x16x32_bf16(av[m], bv1[n], acc[4 + m][n], 0, 0, 0);
    __builtin_amdgcn_s_setprio(0);
    if (pre) { asm volatile("s_waitcnt vmcnt(2)" ::: "memory"); }  // certify A0,A1,B0(t+1)
    __builtin_amdgcn_s_barrier();
  }
#undef STAGE_AH
#undef STAGE_BS

  // epilogue (16x16 C/D): col = lane&15, row = (lane>>4)*4 + reg [m89]
  const int row0 = bm * 256 + wm * 128, col0 = bn * 256 + wn * 64;
#pragma unroll
  for (int m = 0; m < 8; ++m)
#pragma unroll
    for (int n = 0; n < 4; ++n) {
      const int c  = col0 + n * 16 + lr;
      const int rb = row0 + m * 16 + lg * 4;
#pragma unroll
      for (int j = 0; j < 4; ++j) {
        const int r = rb + j;
        const float v = acc[m][n][j];
        if constexpr (EPI == 0) {
          G[(size_t)r * N + c] = f2bf(v);
        } else if constexpr (EPI == 1) {
          float gf = bf2f(G[(size_t)r * N + c]);
          float h = gf / (1.f + __expf(-gf)) * v;
          G[(size_t)r * N + c] = f2bf(h);
        } else {
          __builtin_nontemporal_store(v * Wt[r], &O[(size_t)r * N + c]);
        }
      }
    }

  // fused cvt of the NEXT GEMM's weight (65536 elems/block, grid=896 exact)
  if constexpr (EPI != 2) {
#pragma unroll
    for (int cc = 0; cc < 16; ++cc) {
      const size_t i = (size_t)bid * 65536 + (size_t)cc * 4096 + (size_t)tid * 8;
      float4 a = *(const float4*)(cvtIn + i);
      float4 b = *(const float4*)(cvtIn + i + 4);
      uint4 v;
      v.x = pack2(a.x, a.y); v.y = pack2(a.z, a.w);
      v.z = pack2(b.x, b.y); v.w = pack2(b.z, b.w);
      *(uint4*)(cvtOut + i) = v;
    }
  }
}

extern "C" void kernel_launch(void* const* d_in, const int* in_sizes, int n_in,
                              void* d_out, int out_size, void* d_ws, size_t ws_size,
                              hipStream_t stream) {
  const float* x   = (const float*)d_in[0];
  const float* Wg  = (const float*)d_in[1];
  const float* Wu  = (const float*)d_in[2];
  const float* Wd  = (const float*)d_in[3];
  const int*   top = (const int*)d_in[4];
  const float* wt  = (const float*)d_in[5];
  float* out = (float*)d_out;

  const size_t NE_X = (size_t)NSEL * HIDDEN;
  const size_t NE_W = (size_t)INTER * HIDDEN;
  if (ws_size < (NE_X + 3 * NE_W) * sizeof(uint16_t)) return;

  uint16_t* xs = (uint16_t*)d_ws;
  uint16_t* w1 = xs + NE_X;
  uint16_t* w2 = w1 + NE_W;
  uint16_t* gh = w2 + NE_W;

  const int NCVT = (int)(NE_W / 16384);   // 3584 cvt tail blocks (gather kernel)
  const int nbm  = NSEL / 256;            // 16
  const int ng1  = nbm * (INTER / 256);   // 896
  const int ng3  = nbm * (HIDDEN / 256);  // 256

  // gather x_sel (bf16) + convert Wg -> w1 in one launch
  gather_cast<<<NSEL + NCVT, 256, 0, stream>>>(x, top, xs, Wg, w1);

  // gate: g = x_sel * Wg^T -> gh (bf16); fused cvt Wu -> w2
  gemm_nt<0><<<ng1, 512, 0, stream>>>(xs, w1, gh, nullptr, nullptr,
                                      INTER, HIDDEN, nbm, Wu, w2);
  // up + SwiGLU: h = silu(g) * (x_sel * Wu^T) -> gh; fused cvt Wd -> w1
  gemm_nt<1><<<ng1, 512, 0, stream>>>(xs, w2, gh, nullptr, nullptr,
                                      INTER, HIDDEN, nbm, Wd, w1);
  // down + routing weight: out = (h * Wd^T) * weight[:,None]
  gemm_nt<2><<<ng3, 512, 0, stream>>>(gh, w1, nullptr, out, wt,
                                      HIDDEN, INTER, nbm, nullptr, nullptr);
}

// Round 9
// 1418.059 us; speedup vs baseline: 1.1805x; 1.1805x over previous
//
#include <hip/hip_runtime.h>
#include <hip/hip_bf16.h>
#include <stdint.h>

#define HIDDEN 4096
#define INTER  14336
#define NSEL   4096

using short8 = __attribute__((ext_vector_type(8))) short;
using f32x4  = __attribute__((ext_vector_type(4))) float;

__device__ __forceinline__ uint16_t f2bf(float f) {
  uint32_t u = __float_as_uint(f);
  uint32_t r = (u + 0x7FFFu + ((u >> 16) & 1u)) >> 16;
  return (uint16_t)r;
}
__device__ __forceinline__ uint32_t pack2(float lo, float hi) {
  return (uint32_t)f2bf(lo) | ((uint32_t)f2bf(hi) << 16);
}

// ---- prep: gather x_sel->bf16 (blocks<NSEL) + cvt Wg,Wu,Wd fp32->bf16 ----
__global__ void prep(const float* __restrict__ x, const int* __restrict__ idx,
                     uint16_t* __restrict__ xs,
                     const float* __restrict__ Wg, uint16_t* __restrict__ w1,
                     const float* __restrict__ Wu, uint16_t* __restrict__ w2,
                     const float* __restrict__ Wd, uint16_t* __restrict__ w3,
                     int ncvt) {
  const int b = blockIdx.x;
  const int t = threadIdx.x;
  if (b < NSEL) {
    const size_t s = (size_t)idx[b] * HIDDEN + (size_t)t * 16;
    const size_t d = (size_t)b * HIDDEN + (size_t)t * 16;
    const float4* sp = (const float4*)(x + s);
    float4 f0 = sp[0], f1 = sp[1], f2 = sp[2], f3 = sp[3];
    uint4 v0, v1;
    v0.x = pack2(f0.x, f0.y); v0.y = pack2(f0.z, f0.w);
    v0.z = pack2(f1.x, f1.y); v0.w = pack2(f1.z, f1.w);
    v1.x = pack2(f2.x, f2.y); v1.y = pack2(f2.z, f2.w);
    v1.z = pack2(f3.x, f3.y); v1.w = pack2(f3.z, f3.w);
    *(uint4*)(xs + d)     = v0;
    *(uint4*)(xs + d + 8) = v1;
    return;
  }
  int cb = b - NSEL;
  const float* src; uint16_t* dst;
  if (cb < ncvt)            { src = Wg; dst = w1; }
  else if (cb < 2 * ncvt)   { src = Wu; dst = w2; cb -= ncvt; }
  else                      { src = Wd; dst = w3; cb -= 2 * ncvt; }
#pragma unroll
  for (int k = 0; k < 8; ++k) {
    const size_t i = (size_t)cb * 16384 + (size_t)k * 2048 + (size_t)t * 8;
    float4 a = *(const float4*)(src + i);
    float4 c = *(const float4*)(src + i + 4);
    uint4 v;
    v.x = pack2(a.x, a.y); v.y = pack2(a.z, a.w);
    v.z = pack2(c.x, c.y); v.w = pack2(c.z, c.w);
    *(uint4*)(dst + i) = v;
  }
}

__device__ __forceinline__ void gload16(const void* g, void* l) {
  __builtin_amdgcn_global_load_lds(
      (const __attribute__((address_space(1))) void*)g,
      (__attribute__((address_space(3))) void*)l, 16, 0, 0);
}

__device__ __forceinline__ float silu(float g) {
  return g / (1.f + __expf(-g));
}

// ============================================================================
// Fused NT GEMM, r6-proven schedule host (free-run ring-3, 1 barrier +
// counted vmcnt per K32-tile, zero-conflict swizzle, 16x16x32 MFMA, T1/T5).
// 1024 threads = 16 waves of 64x64 -> 16 waves/CU (the measured wave-count
// lever), acc = 64 VGPR/wave.
// MODE 0 (gate+up fused): BM=256, BN=128, TWO B panels (Wg,Wu); wave
//   (s=w>>3, wm=w&3, wn=(w>>2)&1) computes g (s=0) or u (s=1) for the same
//   output tile. Per tile stage A once (16KB) + Bg (8KB) + Bu (8KB): supply
//   per FLOP halved vs separate GEMMs; g never hits global. Epilogue: g-waves
//   pass acc through LDS to u-waves -> h = silu(g)*u -> bf16 G.
// MODE 1 (down): BM=256, BN=256, single B; out = acc * Wt[row], NT store.
// LDS slot = 32KB (A 16KB + B(s) 16KB), ring-3 = 96KB, 1 block/CU.
// Swizzle (r2/r3/r6 measured-ZERO): line = 2 rows x 32 cols = 128B;
// slot16 = (((r&1)<<2)|lg) ^ ((r>>1)&7); inverse-swizzled global source +
// LINEAR gload_lds dest (rule 21).
// ============================================================================
template<int MODE>
__global__ __launch_bounds__(1024, 4) void gemm_f(
    const uint16_t* __restrict__ A,
    const uint16_t* __restrict__ B0,
    const uint16_t* __restrict__ B1,
    uint16_t* __restrict__ G,
    float* __restrict__ O,
    const float* __restrict__ Wt,
    int N, int K)
{
  __shared__ __align__(16) uint16_t lds[3][16384];  // A[0..8191] | B [8192..16383]

  const int nwg = (int)gridDim.x;
  const int bid = (int)blockIdx.x;
  const int lid = (bid & 7) * (nwg >> 3) + (bid >> 3);
  const int bm = lid & 15, bn = lid >> 4;           // nbm = 16 always

  const int tid  = (int)threadIdx.x;
  const int lane = tid & 63, w = tid >> 6;
  const int lr = lane & 15, lg = lane >> 4;

  int wm, wn, s;
  if constexpr (MODE == 0) { s = w >> 3; wm = w & 3; wn = (w >> 2) & 1; }
  else                     { s = 0;      wm = w & 3; wn = w >> 2;       }

  // ---- fragment read offsets (u16, slot-relative), proven-zero swizzle ----
  int offA[4], offB[4];
#pragma unroll
  for (int m = 0; m < 4; ++m) {
    const int r = wm * 64 + m * 16 + lr;
    offA[m] = (r >> 1) * 64 + (((((r & 1) << 2) | lg) ^ ((r >> 1) & 7)) * 8);
  }
  const int bBase = (MODE == 0) ? (8192 + s * 4096) : 8192;
#pragma unroll
  for (int n = 0; n < 4; ++n) {
    const int r = wn * 64 + n * 16 + lr;
    offB[n] = bBase + (r >> 1) * 64 + (((((r & 1) << 2) | lg) ^ ((r >> 1) & 7)) * 8);
  }

  // ---- staging (inverse-swizzled global source, linear gload_lds dest) ----
  // load0: A chunk per thread (1024 chunks = 256 rows x 32 cols).
  const int suA   = (tid & 7) ^ ((tid >> 3) & 7);
  const int sRowA = 2 * (tid >> 3) + (suA >> 2);
  const int sColA = (suA & 3) * 8;
  const uint16_t* aSrc = A + (size_t)(bm * 256 + sRowA) * K + sColA;
  // load1: B chunk. MODE0: tid<512 -> Bg, tid>=512 -> Bu (j=tid&511, 128 rows).
  //        MODE1: all threads (j=tid, 256 rows).
  const int jB    = (MODE == 0) ? (tid & 511) : tid;
  const int suB   = (jB & 7) ^ ((jB >> 3) & 7);
  const int sRowB = 2 * (jB >> 3) + (suB >> 2);
  const int sColB = (suB & 3) * 8;
  const uint16_t* bSel = (MODE == 0) ? ((tid < 512) ? B0 : B1) : B0;
  const uint16_t* bSrc = bSel + (size_t)(bn * ((MODE == 0) ? 128 : 256) + sRowB) * K + sColB;
  const int bDst = (MODE == 0) ? (8192 + (tid >> 9) * 4096 + (tid & 511) * 8)
                               : (8192 + tid * 8);

#define STAGE(tt, sl) do { \
    gload16(aSrc + (size_t)(tt) * 32, &lds[sl][tid * 8]); \
    gload16(bSrc + (size_t)(tt) * 32, &lds[sl][bDst]); \
  } while (0)

  f32x4 acc[4][4];
#pragma unroll
  for (int m = 0; m < 4; ++m)
#pragma unroll
    for (int n = 0; n < 4; ++n)
#pragma unroll
      for (int j = 0; j < 4; ++j) acc[m][n][j] = 0.f;

  const int nk = K >> 5;

  // prologue: stage tiles 0,1; certify 0 (tile 1's 2 loads stay in flight)
  STAGE(0, 0);
  STAGE(1, 1);
  asm volatile("s_waitcnt vmcnt(2)" ::: "memory");
  __builtin_amdgcn_s_barrier();

  for (int t = 0; t < nk; ++t) {
    const uint16_t* S = &lds[t % 3][0];

    if (t + 2 < nk) STAGE(t + 2, (t + 2) % 3);

    short8 av[4], bv[4];
#pragma unroll
    for (int m = 0; m < 4; ++m) av[m] = *(const short8*)&S[offA[m]];
#pragma unroll
    for (int n = 0; n < 4; ++n) bv[n] = *(const short8*)&S[offB[n]];

    __builtin_amdgcn_s_setprio(1);
#pragma unroll
    for (int m = 0; m < 4; ++m)
#pragma unroll
      for (int n = 0; n < 4; ++n)
        acc[m][n] = __builtin_amdgcn_mfma_f32_16x16x32_bf16(av[m], bv[n], acc[m][n], 0, 0, 0);
    __builtin_amdgcn_s_setprio(0);

    // certify tile t+1; keep t+2's 2 loads in flight (never drain mid-loop)
    if (t + 2 < nk) { asm volatile("s_waitcnt vmcnt(2)" ::: "memory"); }
    else            { asm volatile("s_waitcnt vmcnt(0)" ::: "memory"); }
    __builtin_amdgcn_s_barrier();
  }
#undef STAGE

  // C/D layout: col = lane&15, row = (lane>>4)*4 + reg  [m89-verified]
  if constexpr (MODE == 1) {
    const int row0 = bm * 256 + wm * 64, col0 = bn * 256 + wn * 64;
#pragma unroll
    for (int m = 0; m < 4; ++m)
#pragma unroll
      for (int n = 0; n < 4; ++n) {
        const int c  = col0 + n * 16 + lr;
        const int rb = row0 + m * 16 + lg * 4;
#pragma unroll
        for (int j = 0; j < 4; ++j) {
          const int r = rb + j;
          __builtin_nontemporal_store(acc[m][n][j] * Wt[r], &O[(size_t)r * N + c]);
        }
      }
  } else {
    // g/u exchange: g-wave (s=0) ships acc via LDS to its paired u-wave
    // (s=1, same wm,wn = w-8); u-wave computes h = silu(g)*u, stores bf16.
    float* X = (float*)&lds[0][0];   // 8 g-waves x 4KB = 32KB, loop-dead now
    const int row0 = bm * 256 + wm * 64, col0 = bn * 128 + wn * 64;
#pragma unroll
    for (int m = 0; m < 4; ++m) {
      __builtin_amdgcn_s_barrier();          // prev phase's reads done
      if (s == 0) {
#pragma unroll
        for (int n = 0; n < 4; ++n)
          *(f32x4*)&X[w * 1024 + n * 256 + lr * 16 + lg * 4] = acc[m][n];
      }
      __builtin_amdgcn_s_barrier();          // writes visible
      if (s == 1) {
#pragma unroll
        for (int n = 0; n < 4; ++n) {
          const f32x4 g4 = *(const f32x4*)&X[(w - 8) * 1024 + n * 256 + lr * 16 + lg * 4];
          const int c  = col0 + n * 16 + lr;
          const int rb = row0 + m * 16 + lg * 4;
#pragma unroll
          for (int j = 0; j < 4; ++j)
            G[(size_t)(rb + j) * N + c] = f2bf(silu(g4[j]) * acc[m][n][j]);
        }
      }
    }
  }
}

extern "C" void kernel_launch(void* const* d_in, const int* in_sizes, int n_in,
                              void* d_out, int out_size, void* d_ws, size_t ws_size,
                              hipStream_t stream) {
  const float* x   = (const float*)d_in[0];
  const float* Wg  = (const float*)d_in[1];
  const float* Wu  = (const float*)d_in[2];
  const float* Wd  = (const float*)d_in[3];
  const int*   top = (const int*)d_in[4];
  const float* wt  = (const float*)d_in[5];
  float* out = (float*)d_out;

  const size_t NE_X = (size_t)NSEL * HIDDEN;
  const size_t NE_W = (size_t)INTER * HIDDEN;
  if (ws_size < (NE_X + 3 * NE_W + NE_W) * sizeof(uint16_t)) return;

  uint16_t* xs = (uint16_t*)d_ws;
  uint16_t* w1 = xs + NE_X;    // Wg bf16
  uint16_t* w2 = w1 + NE_W;    // Wu bf16
  uint16_t* w3 = w2 + NE_W;    // Wd bf16
  uint16_t* gh = w3 + NE_W;    // h bf16 [NSEL][INTER]

  const int NCVT = (int)(NE_W / 16384);   // 3584 blocks per weight
  const int ngGU = 16 * (INTER / 128);    // 1792
  const int ngDN = 16 * (HIDDEN / 256);   // 256

  // gather + all three weight cvts in one HBM-stream launch
  prep<<<NSEL + 3 * NCVT, 256, 0, stream>>>(x, top, xs, Wg, w1, Wu, w2, Wd, w3, NCVT);

  // fused gate+up: h = silu(x Wg^T) * (x Wu^T) -> gh (bf16)
  gemm_f<0><<<ngGU, 1024, 0, stream>>>(xs, w1, w2, gh, nullptr, nullptr,
                                       INTER, HIDDEN);
  // down + routing weight: out = (h Wd^T) * weight[:,None]
  gemm_f<1><<<ngDN, 1024, 0, stream>>>(gh, w3, nullptr, nullptr, out, wt,
                                       HIDDEN, INTER);
}